// Round 2
// baseline (1499.797 us; speedup 1.0000x reference)
//
#include <hip/hip_runtime.h>
#include <hip/hip_fp16.h>

#define D 64
#define RB 128            // rows per bin (7-bit local row)
#define NB_MAX 1024       // max bins (n_nodes <= 2^17)
#define NBLK1 512         // P1 blocks
#define P1CAP 6272        // P1 LDS stage capacity (recs) = 50,176 B
#define K7STAGE 1024      // K7 record chunk staged in LDS (8 KB)

typedef unsigned long long ull;
typedef unsigned short u16;

// rec = [ val:f32 (hi32) | localrow:bits17-23 | col:bits0-16 ]
__device__ __forceinline__ ull pack_rec(float v, int r, int c) {
    return ((ull)__float_as_uint(v) << 32) |
           (ull)(((unsigned)(r & (RB - 1)) << 17) | (unsigned)c);
}

// ---------------- fallback: atomic SpMM (guard path) ----------------
__global__ __launch_bounds__(256) void spmm_atomic_kernel(
    const float* __restrict__ x,
    const int*   __restrict__ edge_row,
    const int*   __restrict__ edge_col,
    const float* __restrict__ edge_val,
    float*       __restrict__ out,
    int n_edges)
{
    const int gtid = blockIdx.x * blockDim.x + threadIdx.x;
    const int wave = gtid >> 6;
    const int lane = threadIdx.x & 63;
    if (wave >= n_edges) return;
    const int   r = edge_row[wave];
    const int   c = edge_col[wave];
    const float v = edge_val[wave];
    atomicAdd(&out[(size_t)r * D + lane], v * x[(size_t)c * D + lane]);
}

// ---------------- P1: per-block LDS counting sort + identity-coalesced writeout ----
// (proven in round 0: every global record write is coalesced; counts/startpos
// transposed [bin][blk] so the consumer reads them coalesced)
__global__ __launch_bounds__(256) void p1_localsort_kernel(
    const int* __restrict__ rows, const int* __restrict__ cols,
    const float* __restrict__ vals,
    ull* __restrict__ staged, u16* __restrict__ counts, u16* __restrict__ startpos,
    int n_edges, int nb, int chunk)
{
    __shared__ ull stage[P1CAP];
    __shared__ int cnt[NB_MAX];
    __shared__ int s[256];
    const int t = threadIdx.x, blk = blockIdx.x;
    const int e0 = blk * chunk;
    const int e1 = min(e0 + chunk, n_edges);
    const int len = e1 - e0;

    for (int i = t; i < nb; i += 256) cnt[i] = 0;
    __syncthreads();

    // pass 1: histogram rows (int4)
    for (int i = e0 + t * 4; i < e1; i += 1024) {
        if (i + 4 <= e1) {
            const int4 r4 = *(const int4*)(rows + i);
            atomicAdd(&cnt[r4.x >> 7], 1);
            atomicAdd(&cnt[r4.y >> 7], 1);
            atomicAdd(&cnt[r4.z >> 7], 1);
            atomicAdd(&cnt[r4.w >> 7], 1);
        } else {
            for (int k = i; k < e1; ++k) atomicAdd(&cnt[rows[k] >> 7], 1);
        }
    }
    __syncthreads();

    // write counts + in-place exclusive scan of cnt
    int pre[4], sum = 0;
    const int base = t * 4;
    #pragma unroll
    for (int k = 0; k < 4; ++k) {
        const int idx = base + k;
        const int c = (idx < nb) ? cnt[idx] : 0;
        if (idx < nb) counts[(size_t)idx * NBLK1 + blk] = (u16)c;
        pre[k] = sum; sum += c;
    }
    s[t] = sum;
    for (int off = 1; off < 256; off <<= 1) {
        __syncthreads();
        const int w = (t >= off) ? s[t - off] : 0;
        __syncthreads();
        s[t] += w;
    }
    const int texcl = s[t] - sum;
    __syncthreads();
    #pragma unroll
    for (int k = 0; k < 4; ++k) {
        const int idx = base + k;
        if (idx < nb) {
            const int e = texcl + pre[k];
            cnt[idx] = e;                                   // becomes cursor
            startpos[(size_t)idx * NBLK1 + blk] = (u16)e;
        }
    }
    __syncthreads();

    // pass 2: scatter into LDS stage
    for (int i = e0 + t * 4; i < e1; i += 1024) {
        if (i + 4 <= e1) {
            const int4   r4 = *(const int4*)(rows + i);
            const int4   c4 = *(const int4*)(cols + i);
            const float4 v4 = *(const float4*)(vals + i);
            int p;
            p = atomicAdd(&cnt[r4.x >> 7], 1); stage[p] = pack_rec(v4.x, r4.x, c4.x);
            p = atomicAdd(&cnt[r4.y >> 7], 1); stage[p] = pack_rec(v4.y, r4.y, c4.y);
            p = atomicAdd(&cnt[r4.z >> 7], 1); stage[p] = pack_rec(v4.z, r4.z, c4.z);
            p = atomicAdd(&cnt[r4.w >> 7], 1); stage[p] = pack_rec(v4.w, r4.w, c4.w);
        } else {
            for (int k = i; k < e1; ++k) {
                const int p = atomicAdd(&cnt[rows[k] >> 7], 1);
                stage[p] = pack_rec(vals[k], rows[k], cols[k]);
            }
        }
    }
    __syncthreads();

    // identity-coalesced writeout
    for (int i = t; i < len; i += 256)
        staged[(size_t)blk * chunk + i] = stage[i];
}

// ---------------- P0: x -> fp16 ----------------
__global__ void tohalf_kernel(const float* __restrict__ x,
                              __half2* __restrict__ xh2, int n4)
{
    for (int i = blockIdx.x * blockDim.x + threadIdx.x; i < n4;
         i += gridDim.x * blockDim.x) {
        const float4 v = ((const float4*)x)[i];
        xh2[2 * i + 0] = __floats2half2_rn(v.x, v.y);
        xh2[2 * i + 1] = __floats2half2_rn(v.z, v.w);
    }
}

// ---------------- K7: fused per-bin accumulate -------------------------------------
// block = bin b (128 rows). Streams the bin's records straight from P1's staged
// runs (chunked LDS gather via binary search over run offsets), split-wave half2
// x-gathers with ILP-8 (16 records in flight per wave), ds_add_f32 into a
// 128x64 f32 LDS tile, one coalesced writeout. No sort, no recs round-trip,
// no overflow path (any bin length streams through).
__global__ __launch_bounds__(256) void spmm_bin_kernel(
    const ull* __restrict__ staged,
    const u16* __restrict__ counts,
    const u16* __restrict__ startpos,
    const __half2* __restrict__ xh2,
    float* __restrict__ out,
    int n_nodes, int chunk)
{
    __shared__ float acc[RB * D];        // 32 KB
    __shared__ ull   stage[K7STAGE];     // 8 KB
    __shared__ int   doff[NBLK1 + 1];
    __shared__ int   srcs[NBLK1];
    __shared__ int   s[256];
    const int b = blockIdx.x, t = threadIdx.x;

    // zero acc tile
    for (int i = t; i < RB * D / 4; i += 256)
        ((float4*)acc)[i] = make_float4(0.f, 0.f, 0.f, 0.f);

    // load run lengths + starts (coalesced); exclusive scan over 512 runs
    const int la = (int)counts[(size_t)b * NBLK1 + 2 * t];
    const int lb = (int)counts[(size_t)b * NBLK1 + 2 * t + 1];
    srcs[2 * t]     = (int)startpos[(size_t)b * NBLK1 + 2 * t];
    srcs[2 * t + 1] = (int)startpos[(size_t)b * NBLK1 + 2 * t + 1];
    const int mysum = la + lb;
    s[t] = mysum;
    for (int off = 1; off < 256; off <<= 1) {
        __syncthreads();
        const int w = (t >= off) ? s[t - off] : 0;
        __syncthreads();
        s[t] += w;
    }
    const int excl = s[t] - mysum;
    doff[2 * t] = excl;
    doff[2 * t + 1] = excl + la;
    if (t == 255) doff[NBLK1] = s[255];
    __syncthreads();
    const int len = doff[NBLK1];

    const int lane = t & 63;
    const int wv   = t >> 6;        // wave id 0..3
    const int half = lane >> 5;
    const int fl   = lane & 31;

    for (int c0 = 0; c0 < len; c0 += K7STAGE) {
        const int clen = min(K7STAGE, len - c0);

        // Phase A: gather chunk into LDS stage, 4 binary searches in flight
        {
            int idx[4], lo[4], hi[4];
            #pragma unroll
            for (int k = 0; k < 4; ++k) {
                idx[k] = c0 + t + k * 256;
                lo[k] = 0; hi[k] = NBLK1 - 1;
            }
            for (int step = 0; step < 9; ++step) {
                #pragma unroll
                for (int k = 0; k < 4; ++k) {
                    if (lo[k] < hi[k]) {
                        const int mid = (lo[k] + hi[k] + 1) >> 1;
                        if (doff[mid] <= idx[k]) lo[k] = mid; else hi[k] = mid - 1;
                    }
                }
            }
            #pragma unroll
            for (int k = 0; k < 4; ++k) {
                if (idx[k] < len) {
                    const int r = lo[k];
                    stage[t + k * 256] =
                        staged[(size_t)r * chunk + srcs[r] + (idx[k] - doff[r])];
                }
            }
        }
        __syncthreads();

        // Phase B: split-wave half2 gather + LDS accumulate, ILP-8 (16 recs/wave)
        const int npairs = (clen + 1) >> 1;
        for (int pb = wv * 8; pb < npairs; pb += 32) {
            float vv[8]; int aa[8], lr[8]; bool ok[8];
            #pragma unroll
            for (int k = 0; k < 8; ++k) {
                const int p  = pb + k;
                const int ri = 2 * p + half;
                ok[k] = (p < npairs) && (ri < clen);
                const ull rec = stage[ok[k] ? ri : 0];   // LDS broadcast read
                vv[k] = __uint_as_float((unsigned)(rec >> 32));
                lr[k] = (int)((rec >> 17) & (RB - 1));
                aa[k] = ((int)((unsigned)rec & 0x1FFFF) << 5) + fl;
            }
            __half2 hv[8];
            #pragma unroll
            for (int k = 0; k < 8; ++k) hv[k] = xh2[aa[k]];  // 8 gathers ISSUED
            __builtin_amdgcn_sched_barrier(0);               // ...kept in flight
            #pragma unroll
            for (int k = 0; k < 8; ++k) {
                if (ok[k]) {
                    const float2 xf = __half22float2(hv[k]);
                    atomicAdd(&acc[lr[k] * D + 2 * fl],     vv[k] * xf.x);
                    atomicAdd(&acc[lr[k] * D + 2 * fl + 1], vv[k] * xf.y);
                }
            }
        }
        __syncthreads();
    }

    // coalesced writeout of the 128x64 tile
    const int rowbase = b * RB;
    for (int i = t; i < RB * D / 4; i += 256) {
        const int row = rowbase + (i >> 4);      // 16 float4 per row
        if (row < n_nodes)
            ((float4*)out)[(size_t)rowbase * (D / 4) + i] = ((float4*)acc)[i];
    }
}

static inline size_t align16(size_t v) { return (v + 15) & ~(size_t)15; }

extern "C" void kernel_launch(void* const* d_in, const int* in_sizes, int n_in,
                              void* d_out, int out_size, void* d_ws, size_t ws_size,
                              hipStream_t stream)
{
    // setup_inputs order: t, x, edge_row, edge_col, edge_val
    const float* x        = (const float*)d_in[1];
    const int*   edge_row = (const int*)d_in[2];
    const int*   edge_col = (const int*)d_in[3];
    const float* edge_val = (const float*)d_in[4];
    float*       out      = (float*)d_out;

    const int n_edges = in_sizes[2];
    const int n_nodes = out_size / D;
    const int nb      = (n_nodes + RB - 1) / RB;
    const int chunk   = (((n_edges + NBLK1 - 1) / NBLK1) + 3) & ~3;  // x4 for int4

    // workspace carve
    const size_t off_staged = 0;                                             // NBLK1*chunk*8
    const size_t off_xh     = align16(off_staged + (size_t)NBLK1 * chunk * 8);
    const size_t off_counts = align16(off_xh + (size_t)n_nodes * D * 2);     // nb*NBLK1 u16
    const size_t off_start  = align16(off_counts + (size_t)nb * NBLK1 * 2);  // nb*NBLK1 u16
    const size_t ws_needed  = off_start + (size_t)nb * NBLK1 * 2;

    if (ws_size < ws_needed || nb > NB_MAX || n_nodes > (1 << 17) ||
        chunk > P1CAP || n_edges < 1) {
        hipMemsetAsync(out, 0, (size_t)out_size * sizeof(float), stream);
        const int n_blocks = (n_edges + 3) / 4;
        spmm_atomic_kernel<<<n_blocks, 256, 0, stream>>>(
            x, edge_row, edge_col, edge_val, out, n_edges);
        return;
    }

    char*   ws       = (char*)d_ws;
    ull*    staged   = (ull*)(ws + off_staged);
    __half* xh       = (__half*)(ws + off_xh);
    u16*    counts   = (u16*)(ws + off_counts);
    u16*    startpos = (u16*)(ws + off_start);

    // P0: x -> fp16 (independent of P1)
    const int n4 = (n_nodes * D) / 4;
    tohalf_kernel<<<2048, 256, 0, stream>>>(x, (__half2*)xh, n4);
    // P1: per-block LDS counting sort -> staged (all record writes coalesced)
    p1_localsort_kernel<<<NBLK1, 256, 0, stream>>>(
        edge_row, edge_col, edge_val, staged, counts, startpos,
        n_edges, nb, chunk);
    // K7: fused per-bin gather + accumulate + writeout
    spmm_bin_kernel<<<nb, 256, 0, stream>>>(
        staged, counts, startpos, (const __half2*)xh, out, n_nodes, chunk);
}

// Round 3
// 259.110 us; speedup vs baseline: 5.7883x; 5.7883x over previous
//
#include <hip/hip_runtime.h>
#include <hip/hip_bf16.h>
#include <hip/hip_fp16.h>

#define D 64
#define RB 128            // rows per bin (7-bit local row)
#define NB_MAX 1024       // max bins (n_nodes <= 2^17)
#define NBLK1 512         // P1 blocks (2/CU, 8 waves/CU)
#define P1CAP 6272        // P1 LDS stage capacity (recs) = 50,176 B
#define CAP 5120          // P4 LDS stage capacity (recs) = 40 KB

typedef unsigned long long ull;
typedef unsigned short u16;

// rec = [ val:f32 (hi32) | localrow:bits17-23 | col:bits0-16 ]
__device__ __forceinline__ ull pack_rec(float v, int r, int c) {
    return ((ull)__float_as_uint(v) << 32) |
           (ull)(((unsigned)(r & (RB - 1)) << 17) | (unsigned)c);
}

// ---------------- fallback: round-1 atomic kernel ----------------
__global__ __launch_bounds__(256) void spmm_atomic_kernel(
    const float* __restrict__ x,
    const int*   __restrict__ edge_row,
    const int*   __restrict__ edge_col,
    const float* __restrict__ edge_val,
    float*       __restrict__ out,
    int n_edges)
{
    const int gtid = blockIdx.x * blockDim.x + threadIdx.x;
    const int wave = gtid >> 6;
    const int lane = threadIdx.x & 63;
    if (wave >= n_edges) return;
    const int   r = edge_row[wave];
    const int   c = edge_col[wave];
    const float v = edge_val[wave];
    atomicAdd(&out[(size_t)r * D + lane], v * x[(size_t)c * D + lane]);
}

// ---------------- P1: per-block LDS counting sort + identity-coalesced writeout ----
// counts/startpos layout: [bin][blk] (transposed) -> P2/P4 reads coalesced;
// P1's strided u16 writes hit a 100KB L2-resident array (absorbed).
__global__ __launch_bounds__(256) void p1_localsort_kernel(
    const int* __restrict__ rows, const int* __restrict__ cols,
    const float* __restrict__ vals,
    ull* __restrict__ staged, u16* __restrict__ counts, u16* __restrict__ startpos,
    int n_edges, int nb, int chunk)
{
    __shared__ ull stage[P1CAP];
    __shared__ int cnt[NB_MAX];
    __shared__ int s[256];
    const int t = threadIdx.x, blk = blockIdx.x;
    const int e0 = blk * chunk;
    const int e1 = min(e0 + chunk, n_edges);
    const int len = e1 - e0;

    for (int i = t; i < nb; i += 256) cnt[i] = 0;
    __syncthreads();

    // pass 1: histogram rows (int4)
    for (int i = e0 + t * 4; i < e1; i += 1024) {
        if (i + 4 <= e1) {
            const int4 r4 = *(const int4*)(rows + i);
            atomicAdd(&cnt[r4.x >> 7], 1);
            atomicAdd(&cnt[r4.y >> 7], 1);
            atomicAdd(&cnt[r4.z >> 7], 1);
            atomicAdd(&cnt[r4.w >> 7], 1);
        } else {
            for (int k = i; k < e1; ++k) atomicAdd(&cnt[rows[k] >> 7], 1);
        }
    }
    __syncthreads();

    // write counts + in-place exclusive scan of cnt
    int pre[4], sum = 0;
    const int base = t * 4;
    #pragma unroll
    for (int k = 0; k < 4; ++k) {
        const int idx = base + k;
        const int c = (idx < nb) ? cnt[idx] : 0;
        if (idx < nb) counts[(size_t)idx * NBLK1 + blk] = (u16)c;
        pre[k] = sum; sum += c;
    }
    s[t] = sum;
    for (int off = 1; off < 256; off <<= 1) {
        __syncthreads();
        const int w = (t >= off) ? s[t - off] : 0;
        __syncthreads();
        s[t] += w;
    }
    const int texcl = s[t] - sum;
    __syncthreads();
    #pragma unroll
    for (int k = 0; k < 4; ++k) {
        const int idx = base + k;
        if (idx < nb) {
            const int e = texcl + pre[k];
            cnt[idx] = e;                                   // becomes cursor
            startpos[(size_t)idx * NBLK1 + blk] = (u16)e;
        }
    }
    __syncthreads();

    // pass 2: scatter into LDS stage
    for (int i = e0 + t * 4; i < e1; i += 1024) {
        if (i + 4 <= e1) {
            const int4   r4 = *(const int4*)(rows + i);
            const int4   c4 = *(const int4*)(cols + i);
            const float4 v4 = *(const float4*)(vals + i);
            int p;
            p = atomicAdd(&cnt[r4.x >> 7], 1); stage[p] = pack_rec(v4.x, r4.x, c4.x);
            p = atomicAdd(&cnt[r4.y >> 7], 1); stage[p] = pack_rec(v4.y, r4.y, c4.y);
            p = atomicAdd(&cnt[r4.z >> 7], 1); stage[p] = pack_rec(v4.z, r4.z, c4.z);
            p = atomicAdd(&cnt[r4.w >> 7], 1); stage[p] = pack_rec(v4.w, r4.w, c4.w);
        } else {
            for (int k = i; k < e1; ++k) {
                const int p = atomicAdd(&cnt[rows[k] >> 7], 1);
                stage[p] = pack_rec(vals[k], rows[k], cols[k]);
            }
        }
    }
    __syncthreads();

    // identity-coalesced writeout
    for (int i = t; i < len; i += 256)
        staged[(size_t)blk * chunk + i] = stage[i];
}

// ---------------- P2: binsum[b] = sum over blocks of counts[b][blk] (coalesced) ----
__global__ __launch_bounds__(256) void p2_binsum_kernel(
    const u16* __restrict__ counts, int* __restrict__ binsum, int nb)
{
    __shared__ int s[256];
    const int b = blockIdx.x, t = threadIdx.x;
    const int acc = (int)counts[(size_t)b * NBLK1 + t] +
                    (int)counts[(size_t)b * NBLK1 + t + 256];
    s[t] = acc;
    __syncthreads();
    for (int off = 128; off > 0; off >>= 1) {
        if (t < off) s[t] += s[t + off];
        __syncthreads();
    }
    if (t == 0) binsum[b] = s[0];
}

// ---------------- P3: exclusive scan over bins -> binbase[nb+1]; zero flags --------
__global__ __launch_bounds__(1024) void p3_scanbins_kernel(
    const int* __restrict__ binsum, int* __restrict__ binbase,
    int* __restrict__ flags, int nb)
{
    __shared__ int s[1024];
    const int t = threadIdx.x;
    const int mine = (t < nb) ? binsum[t] : 0;
    s[t] = mine;
    for (int off = 1; off < 1024; off <<= 1) {
        __syncthreads();
        const int v = (t >= off) ? s[t - off] : 0;
        __syncthreads();
        s[t] += v;
    }
    if (t < nb) { binbase[t] = s[t] - mine; flags[t] = 0; }
    if (t == nb - 1) binbase[nb] = s[t];
}

// ---------------- P4: per-bin gather + LDS key-sort (localrow | colslice) ----------
__global__ __launch_bounds__(256) void p4_binsort_kernel(
    const ull* __restrict__ staged, const u16* __restrict__ counts,
    const u16* __restrict__ startpos, const int* __restrict__ binbase,
    ull* __restrict__ recs, int* __restrict__ offsets_row, int* __restrict__ flags,
    int nb, int n_nodes, int chunk)
{
    __shared__ ull stage[CAP];
    __shared__ int doff[NBLK1 + 1];
    __shared__ int srcs[NBLK1];
    __shared__ int cnt[1024];
    __shared__ int s[256];
    const int b = blockIdx.x, t = threadIdx.x;
    const int s0 = binbase[b];

    // load run lengths + starts (coalesced); exclusive scan over 512 runs
    const int la = (int)counts[(size_t)b * NBLK1 + 2 * t];
    const int lb = (int)counts[(size_t)b * NBLK1 + 2 * t + 1];
    srcs[2 * t]     = (int)startpos[(size_t)b * NBLK1 + 2 * t];
    srcs[2 * t + 1] = (int)startpos[(size_t)b * NBLK1 + 2 * t + 1];
    const int mysum = la + lb;
    s[t] = mysum;
    for (int off = 1; off < 256; off <<= 1) {
        __syncthreads();
        const int w = (t >= off) ? s[t - off] : 0;
        __syncthreads();
        s[t] += w;
    }
    const int excl = s[t] - mysum;
    doff[2 * t] = excl;
    doff[2 * t + 1] = excl + la;
    if (t == 255) doff[NBLK1] = s[255];
    __syncthreads();
    const int len = doff[NBLK1];

    if (len > CAP) {
        // overflow: bin-grouped raw copy (K6 filter path)
        if (t == 0) flags[b] = 1;
        for (int i = t; i < len; i += 256) {
            int lo = 0, hi = NBLK1 - 1;
            while (lo < hi) {
                const int mid = (lo + hi + 1) >> 1;
                if (doff[mid] <= i) lo = mid; else hi = mid - 1;
            }
            recs[s0 + i] = staged[(size_t)lo * chunk + srcs[lo] + (i - doff[lo])];
        }
        if (t == 0 && b * RB <= n_nodes) offsets_row[b * RB] = s0;
        return;
    }

    for (int i = t; i < 1024; i += 256) cnt[i] = 0;
    __syncthreads();

    // gather runs into LDS + key histogram
    for (int i = t; i < len; i += 256) {
        int lo = 0, hi = NBLK1 - 1;
        while (lo < hi) {
            const int mid = (lo + hi + 1) >> 1;
            if (doff[mid] <= i) lo = mid; else hi = mid - 1;
        }
        const ull rr = staged[(size_t)lo * chunk + srcs[lo] + (i - doff[lo])];
        stage[i] = rr;
        const int key = ((int)((rr >> 17) & (RB - 1)) << 3) |
                        (int)(((unsigned)rr & 0x1FFFF) >> 14);
        atomicAdd(&cnt[key], 1);
    }
    __syncthreads();

    // exclusive scan of 1024 keys (4 per thread) -> cnt becomes cursor
    int v[4], pre[4], sum = 0;
    const int base = t * 4;
    #pragma unroll
    for (int k = 0; k < 4; ++k) { v[k] = cnt[base + k]; pre[k] = sum; sum += v[k]; }
    s[t] = sum;
    for (int off = 1; off < 256; off <<= 1) {
        __syncthreads();
        const int w = (t >= off) ? s[t - off] : 0;
        __syncthreads();
        s[t] += w;
    }
    const int texcl = s[t] - sum;
    __syncthreads();
    #pragma unroll
    for (int k = 0; k < 4; ++k) cnt[base + k] = texcl + pre[k];
    __syncthreads();

    // emit row offsets (row lr starts at key lr*8)
    if (t <= RB) {
        const int r = b * RB + t;
        if (r <= n_nodes)
            offsets_row[r] = s0 + ((t == RB) ? len : cnt[t << 3]);
    }
    __syncthreads();

    // permute to final (localrow, colslice) order
    for (int i = t; i < len; i += 256) {
        const ull rr = stage[i];
        const int key = ((int)((rr >> 17) & (RB - 1)) << 3) |
                        (int)(((unsigned)rr & 0x1FFFF) >> 14);
        const int p = atomicAdd(&cnt[key], 1);
        recs[s0 + p] = rr;
    }
}

// ---------------- P0: x -> fp16 (xh reuses the staged region after P4) -------------
__global__ void tohalf_kernel(const float* __restrict__ x,
                              __half2* __restrict__ xh2, int n4)
{
    for (int i = blockIdx.x * blockDim.x + threadIdx.x; i < n4;
         i += gridDim.x * blockDim.x) {
        const float4 v = ((const float4*)x)[i];
        xh2[2 * i + 0] = __floats2half2_rn(v.x, v.y);
        xh2[2 * i + 1] = __floats2half2_rn(v.z, v.w);
    }
}

// ---------------- K6h2: CSR SpMM, split-wave half2 gathers, 16 edges in flight -----
// Lanes 0-31 take even records, 32-63 odd records; each lane loads one __half2
// (dword), so one gather instruction covers 2 records and the ILP-8 batch keeps
// 16 records in flight (2x round-0 MLP at identical TLP). Masked full batch for
// the tail keeps the pipeline 8-deep. Halves combined via one shfl_xor(32).
__global__ __launch_bounds__(256, 8) void spmm_csr_half2_kernel(
    const __half* __restrict__ xh,
    const int*   __restrict__ offsets_row,
    const int*   __restrict__ binbase,
    const ull*   __restrict__ recs,
    const int*   __restrict__ flags,
    float*       __restrict__ out,
    int n_nodes)
{
    const int row  = blockIdx.x * 4 + (threadIdx.x >> 6);
    if (row >= n_nodes) return;
    const int lane = threadIdx.x & 63;
    const int b    = row >> 7;

    if (__builtin_expect(flags[b], 0)) {
        // overflow path: unsorted bin-grouped records, full-wave scalar
        float acc = 0.f;
        const int s  = binbase[b];
        const int e  = binbase[b + 1];
        const int lr = row & (RB - 1);
        for (int j = s; j < e; ++j) {
            const ull rec = recs[j];
            if ((int)((rec >> 17) & (RB - 1)) == lr) {
                const int   c = (int)((unsigned)rec & 0x1FFFF);
                const float v = __uint_as_float((unsigned)(rec >> 32));
                acc += v * __half2float(xh[(size_t)c * D + lane]);
            }
        }
        out[(size_t)row * D + lane] = acc;
        return;
    }

    const __half2* xh2 = (const __half2*)xh;
    const int half = lane >> 5;
    const int fl   = lane & 31;

    const int s = offsets_row[row];
    const int e = offsets_row[row + 1];
    float accx = 0.f, accy = 0.f;

    int j = s;
    // full batches: 16 records, 8 gathers in flight
    for (; j + 16 <= e; j += 16) {
        float vv[8]; int aa[8];
        #pragma unroll
        for (int k = 0; k < 8; ++k) {
            const ull rec = recs[j + 2 * k + half];
            vv[k] = __uint_as_float((unsigned)(rec >> 32));
            aa[k] = ((int)((unsigned)rec & 0x1FFFF) << 5) + fl;
        }
        __half2 hv[8];
        #pragma unroll
        for (int k = 0; k < 8; ++k) hv[k] = xh2[aa[k]];   // 8 gathers = 16 recs ISSUED
        __builtin_amdgcn_sched_barrier(0);                // ...kept in flight
        #pragma unroll
        for (int k = 0; k < 8; ++k) {
            const float2 xf = __half22float2(hv[k]);
            accx = fmaf(vv[k], xf.x, accx);
            accy = fmaf(vv[k], xf.y, accy);
        }
    }
    // single masked batch for the tail: pipeline stays 8-deep
    if (j < e) {
        const int safe = e - 1;
        float vv[8]; int aa[8];
        #pragma unroll
        for (int k = 0; k < 8; ++k) {
            const int  idx = j + 2 * k + half;
            const bool ok  = idx < e;
            const ull  rec = recs[ok ? idx : safe];
            vv[k] = ok ? __uint_as_float((unsigned)(rec >> 32)) : 0.f;
            aa[k] = ((int)((unsigned)rec & 0x1FFFF) << 5) + fl;
        }
        __half2 hv[8];
        #pragma unroll
        for (int k = 0; k < 8; ++k) hv[k] = xh2[aa[k]];
        __builtin_amdgcn_sched_barrier(0);
        #pragma unroll
        for (int k = 0; k < 8; ++k) {
            const float2 xf = __half22float2(hv[k]);
            accx = fmaf(vv[k], xf.x, accx);
            accy = fmaf(vv[k], xf.y, accy);
        }
    }

    accx += __shfl_xor(accx, 32);
    accy += __shfl_xor(accy, 32);
    if (half == 0) {
        float2 o; o.x = accx; o.y = accy;
        ((float2*)out)[(size_t)row * 32 + fl] = o;
    }
}

static inline size_t align16(size_t v) { return (v + 15) & ~(size_t)15; }

extern "C" void kernel_launch(void* const* d_in, const int* in_sizes, int n_in,
                              void* d_out, int out_size, void* d_ws, size_t ws_size,
                              hipStream_t stream)
{
    // setup_inputs order: t, x, edge_row, edge_col, edge_val
    const float* x        = (const float*)d_in[1];
    const int*   edge_row = (const int*)d_in[2];
    const int*   edge_col = (const int*)d_in[3];
    const float* edge_val = (const float*)d_in[4];
    float*       out      = (float*)d_out;

    const int n_edges = in_sizes[2];
    const int n_nodes = out_size / D;
    const int nb      = (n_nodes + RB - 1) / RB;
    const int chunk   = (((n_edges + NBLK1 - 1) / NBLK1) + 3) & ~3;  // x4 for int4

    // workspace carve
    const size_t off_recs    = 0;                                               // n_edges*8
    const size_t off_staged  = align16(off_recs + (size_t)n_edges * 8);         // NBLK1*chunk*8 (xh reuse)
    const size_t off_counts  = align16(off_staged + (size_t)NBLK1 * chunk * 8); // nb*NBLK1 u16
    const size_t off_start   = align16(off_counts + (size_t)nb * NBLK1 * 2);    // nb*NBLK1 u16
    const size_t off_binsum  = align16(off_start + (size_t)nb * NBLK1 * 2);     // nb ints
    const size_t off_binbase = align16(off_binsum + (size_t)nb * 4);            // nb+1 ints
    const size_t off_rowoffs = align16(off_binbase + (size_t)(nb + 1) * 4);     // n_nodes+1 ints
    const size_t off_flags   = align16(off_rowoffs + (size_t)(n_nodes + 1) * 4);// nb ints
    const size_t ws_needed   = off_flags + (size_t)nb * 4;
    const size_t xh_bytes    = (size_t)n_nodes * D * 2;   // must fit in staged region

    if (ws_size < ws_needed || nb > NB_MAX || n_nodes > (1 << 17) ||
        chunk > P1CAP || xh_bytes > (size_t)NBLK1 * chunk * 8) {
        hipMemsetAsync(out, 0, (size_t)out_size * sizeof(float), stream);
        const int n_blocks = (n_edges + 3) / 4;
        spmm_atomic_kernel<<<n_blocks, 256, 0, stream>>>(
            x, edge_row, edge_col, edge_val, out, n_edges);
        return;
    }

    char* ws = (char*)d_ws;
    ull*    recs        = (ull*)(ws + off_recs);
    ull*    staged      = (ull*)(ws + off_staged);
    u16*    counts      = (u16*)(ws + off_counts);
    u16*    startpos    = (u16*)(ws + off_start);
    int*    binsum      = (int*)(ws + off_binsum);
    int*    binbase     = (int*)(ws + off_binbase);
    int*    offsets_row = (int*)(ws + off_rowoffs);
    int*    flags       = (int*)(ws + off_flags);
    __half* xh          = (__half*)(ws + off_staged);   // reuses staged AFTER P4

    // P1: per-block LDS counting sort -> staged (all record writes coalesced)
    p1_localsort_kernel<<<NBLK1, 256, 0, stream>>>(
        edge_row, edge_col, edge_val, staged, counts, startpos,
        n_edges, nb, chunk);
    // P2: per-bin totals
    p2_binsum_kernel<<<nb, 256, 0, stream>>>(counts, binsum, nb);
    // P3: bin bases + flag zeroing
    p3_scanbins_kernel<<<1, 1024, 0, stream>>>(binsum, binbase, flags, nb);
    // P4: gather runs + sort by (localrow | colslice) -> final recs + row offsets
    p4_binsort_kernel<<<nb, 256, 0, stream>>>(
        staged, counts, startpos, binbase, recs, offsets_row, flags,
        nb, n_nodes, chunk);
    // P0: x -> fp16 into the (now free) staged region
    const int n4 = (n_nodes * D) / 4;
    tohalf_kernel<<<2048, 256, 0, stream>>>(x, (__half2*)xh, n4);
    // K6h2: CSR SpMM, split-wave half2 gathers
    spmm_csr_half2_kernel<<<(n_nodes + 3) / 4, 256, 0, stream>>>(
        xh, offsets_row, binbase, recs, flags, out, n_nodes);
}